// Round 9
// baseline (233.784 us; speedup 1.0000x reference)
//
#include <hip/hip_runtime.h>

// CompressibleFluidLoss: out[i] = mean_x + mean_y + (p[i]-p_prev[i])/dt,
// vp = v*p per node; means are masked scatter-means over edges at src.
//
// Round 9: r8's sweep_scatter writes 8B records to 64 different bucket
// streams per wave -> 2.7x write amplification (182MB for 67MB payload).
// Fix: block-local LDS tile-sort. Per 1024-edge tile: classify -> LDS
// histogram -> LDS scan -> stage records grouped by bucket -> flush with
// consecutive threads writing consecutive records of each bucket run
// (avg 4 recs = 32B). Global layout identical to r8 (per-block cursors
// walk start[k] = base[k] + scanned[k][b]).

#define NPB      2048   // nodes per bucket
#define NPB_LOG  11
#define MAXBUCK  512
#define NBLK     1024   // sweep grid blocks (counts matrix width)
#define SWT      1024   // sweep block threads
#define TILE_REC (2 * SWT)

// ---------------- fast path ----------------

__global__ void node_pre_fast(const float2* __restrict__ v,
                              const float* __restrict__ p,
                              float2* __restrict__ vp, int N) {
    int i = blockIdx.x * blockDim.x + threadIdx.x;
    int stride = gridDim.x * blockDim.x;
    for (; i < N; i += stride) {
        float2 vi = v[i];
        float pi = p[i];
        vp[i] = make_float2(vi.x * pi, vi.y * pi);
    }
}

// per-direction record counting: 0,1,2 records per edge
__global__ void sweep_count(const int* __restrict__ src_idx,
                            const float2* __restrict__ ea,
                            int* __restrict__ counts, int nbuck, int E) {
    __shared__ int hist[MAXBUCK];
    for (int i = threadIdx.x; i < nbuck; i += blockDim.x) hist[i] = 0;
    __syncthreads();
    int b = blockIdx.x;
    for (int e = b * SWT + threadIdx.x; e < E; e += NBLK * SWT) {
        float2 a = ea[e];
        int nrec = (a.x != 0.f) + (a.y != 0.f);
        if (nrec) atomicAdd(&hist[src_idx[e] >> NPB_LOG], nrec);
    }
    __syncthreads();
    for (int i = threadIdx.x; i < nbuck; i += blockDim.x)
        counts[(size_t)i * NBLK + b] = hist[i];
}

// one block (1024 threads) per bucket row: exclusive scan over NBLK entries
__global__ void scan_rows(const int* __restrict__ counts,
                          int* __restrict__ scanned,
                          int* __restrict__ totals) {
    __shared__ int buf[NBLK];
    int k = blockIdx.x, t = threadIdx.x;
    int v = counts[(size_t)k * NBLK + t];
    buf[t] = v;
    __syncthreads();
    for (int off = 1; off < NBLK; off <<= 1) {
        int x = (t >= off) ? buf[t - off] : 0;
        __syncthreads();
        buf[t] += x;
        __syncthreads();
    }
    scanned[(size_t)k * NBLK + t] = buf[t] - v;   // exclusive
    if (t == NBLK - 1) totals[k] = buf[t];
}

__global__ void scan_totals(const int* __restrict__ totals,
                            int* __restrict__ base, int nbuck) {
    __shared__ int buf[1024];
    int t = threadIdx.x;
    int v = (t < nbuck) ? totals[t] : 0;
    buf[t] = v;
    __syncthreads();
    for (int off = 1; off < 1024; off <<= 1) {
        int x = (t >= off) ? buf[t - off] : 0;
        __syncthreads();
        buf[t] += x;
        __syncthreads();
    }
    if (t < nbuck) base[t] = buf[t] - v;
}

// gather-free bucketing with block-local LDS tile-sort; 8B records
// {meta = s_local | dir<<11 | d<<12, a_bits}
__global__ void sweep_scatter(const float2* __restrict__ ea,
                              const int* __restrict__ src_idx,
                              const int* __restrict__ dst_idx,
                              const int* __restrict__ scanned,
                              const int* __restrict__ base,
                              uint2* __restrict__ recs, int nbuck, int E) {
    __shared__ uint2 stage[TILE_REC];   // 16 KB, records grouped by bucket
    __shared__ int hist[MAXBUCK];       // per-tile bucket counts
    __shared__ int tl[MAXBUCK];         // inclusive scan of hist
    __shared__ int gcur[MAXBUCK];       // running global cursor per bucket
    __shared__ int gdst[MAXBUCK];       // frozen cursor for this tile's flush
    int b = blockIdx.x;
    int t = threadIdx.x;
    for (int i = t; i < nbuck; i += SWT)
        gcur[i] = base[i] + scanned[(size_t)i * NBLK + b];

    int ntile = (E + NBLK * SWT - 1) / (NBLK * SWT);   // uniform across blocks
    for (int tile = 0; tile < ntile; ++tile) {
        __syncthreads();   // protects hist/stage reuse vs previous flush
        for (int i = t; i < nbuck; i += SWT) hist[i] = 0;
        __syncthreads();

        int e = (tile * NBLK + b) * SWT + t;   // same edge->block map as sweep_count
        int k = 0, off = 0, nrec = 0;
        uint2 r0, r1;
        if (e < E) {
            float2 a = ea[e];
            bool mx = (a.x != 0.f);
            bool my = (a.y != 0.f);
            if (mx || my) {
                int s = src_idx[e];
                int d = dst_idx[e];
                k = s >> NPB_LOG;
                unsigned sl = (unsigned)(s & (NPB - 1));
                unsigned dm = (unsigned)d << 12;
                nrec = (int)mx + (int)my;
                uint2 rx = make_uint2(sl | dm, __float_as_uint(a.x));
                uint2 ry = make_uint2(sl | 0x800u | dm, __float_as_uint(a.y));
                r0 = mx ? rx : ry;
                r1 = ry;
                off = atomicAdd(&hist[k], nrec);
            }
        }
        __syncthreads();
        // inclusive scan hist -> tl (nbuck <= 512 < 1024 threads)
        if (t < nbuck) tl[t] = hist[t];
        __syncthreads();
        for (int ofs = 1; ofs < nbuck; ofs <<= 1) {
            int x = 0;
            if (t < nbuck && t >= ofs) x = tl[t - ofs];
            __syncthreads();
            if (t < nbuck) tl[t] += x;
            __syncthreads();
        }
        // stage records grouped by bucket; freeze this tile's global dests
        if (nrec) {
            int p0 = tl[k] - hist[k] + off;
            stage[p0] = r0;
            if (nrec == 2) stage[p0 + 1] = r1;
        }
        if (t < nbuck) gdst[t] = gcur[t];
        __syncthreads();
        // flush: consecutive threads -> consecutive records of each bucket run
        int total = tl[nbuck - 1];
        for (int idx = t; idx < total; idx += SWT) {
            int lo = 0, hi = nbuck - 1;        // first k with tl[k] > idx
            while (lo < hi) {
                int mid = (lo + hi) >> 1;
                if (tl[mid] > idx) hi = mid; else lo = mid + 1;
            }
            int excl = tl[lo] - hist[lo];
            recs[gdst[lo] + (idx - excl)] = stage[idx];
        }
        if (t < nbuck) gcur[t] += hist[t];     // advance cursors (read next tile)
    }
}

__global__ void bucket_reduce(const uint2* __restrict__ recs,
                              const int* __restrict__ base,
                              const int* __restrict__ totals,
                              const float2* __restrict__ vp,
                              const float* __restrict__ p,
                              const float* __restrict__ p_prev,
                              const float* __restrict__ dt_ptr,
                              float* __restrict__ out, int N) {
    __shared__ float2 vps[NPB];    // 16 KB — bucket-local vp, coalesced stage
    __shared__ float4 acc[NPB];    // 32 KB
    int k = blockIdx.x;
    int g0 = k * NPB;
    for (int i = threadIdx.x; i < NPB; i += blockDim.x) {
        int g = g0 + i;
        vps[i] = (g < N) ? vp[g] : make_float2(0.f, 0.f);
        acc[i] = make_float4(0.f, 0.f, 0.f, 0.f);
    }
    __syncthreads();
    int b0 = base[k], n = totals[k];
    for (int i = threadIdx.x; i < n; i += blockDim.x) {
        uint2 r = recs[b0 + i];
        unsigned sl = r.x & (NPB - 1u);
        bool diry = (r.x & 0x800u) != 0u;
        int d = (int)(r.x >> 12);
        float a = __uint_as_float(r.y);
        float2 vpd = vp[d];          // the one random gather (L2/L3-resident)
        float2 vs = vps[sl];
        float c = (diry ? (vpd.y - vs.y) : (vpd.x - vs.x)) / a;
        float* A = (float*)&acc[sl];
        if (diry) { atomicAdd(A + 2, c); atomicAdd(A + 3, 1.f); }
        else      { atomicAdd(A + 0, c); atomicAdd(A + 1, 1.f); }
    }
    __syncthreads();
    float inv_dt = 1.0f / dt_ptr[0];
    for (int i = threadIdx.x; i < NPB; i += blockDim.x) {
        int g = g0 + i;
        if (g < N) {
            float4 A = acc[i];
            out[g] = A.x / fmaxf(A.y, 1.f) + A.z / fmaxf(A.w, 1.f)
                   + (p[g] - p_prev[g]) * inv_dt;
        }
    }
}

// ---------------- fallback path (round-5: f64-packed atomics) ----------------

#define K_OFF 1073741824.0   // 2^30

__global__ void fb_node_pre(const float2* __restrict__ v,
                            const float* __restrict__ p,
                            float2* __restrict__ vp,
                            double2* __restrict__ acc, int N) {
    int i = blockIdx.x * blockDim.x + threadIdx.x;
    int stride = gridDim.x * blockDim.x;
    for (; i < N; i += stride) {
        float2 vi = v[i];
        float pi = p[i];
        vp[i] = make_float2(vi.x * pi, vi.y * pi);
        acc[i] = make_double2(0.0, 0.0);
    }
}

__global__ void fb_edge_scatter(const float2* __restrict__ vp,
                                const float2* __restrict__ ea,
                                const int* __restrict__ src_idx,
                                const int* __restrict__ dst_idx,
                                double2* __restrict__ acc, int E) {
    int e = blockIdx.x * blockDim.x + threadIdx.x;
    if (e >= E) return;
    float2 a = ea[e];
    bool mx = (a.x != 0.f);
    bool my = (a.y != 0.f);
    if (!mx && !my) return;
    int s = src_idx[e];
    int d = dst_idx[e];
    float2 vs = vp[s];
    float2 vd = vp[d];
    double* basep = (double*)&acc[s];
    if (mx) unsafeAtomicAdd(basep + 0, (double)((vd.x - vs.x) / a.x) + K_OFF);
    if (my) unsafeAtomicAdd(basep + 1, (double)((vd.y - vs.y) / a.y) + K_OFF);
}

__global__ void fb_node_final(const double2* __restrict__ acc,
                              const float* __restrict__ p,
                              const float* __restrict__ p_prev,
                              const float* __restrict__ dt_ptr,
                              float* __restrict__ out, int N) {
    int i = blockIdx.x * blockDim.x + threadIdx.x;
    int stride = gridDim.x * blockDim.x;
    float inv_dt = 1.0f / dt_ptr[0];
    for (; i < N; i += stride) {
        double2 A = acc[i];
        double cx = rint(A.x * (1.0 / K_OFF));
        double sx = A.x - cx * K_OFF;
        double cy = rint(A.y * (1.0 / K_OFF));
        double sy = A.y - cy * K_OFF;
        out[i] = (float)(sx / fmax(cx, 1.0)) + (float)(sy / fmax(cy, 1.0))
               + (p[i] - p_prev[i]) * inv_dt;
    }
}

// ---------------- launch ----------------

extern "C" void kernel_launch(void* const* d_in, const int* in_sizes, int n_in,
                              void* d_out, int out_size, void* d_ws, size_t ws_size,
                              hipStream_t stream) {
    const float2* v_x    = (const float2*)d_in[0];
    const float*  p_x    = (const float*)d_in[2];
    const float*  p_prev = (const float*)d_in[3];
    const float*  dt     = (const float*)d_in[9];
    const float2* ea     = (const float2*)d_in[10];
    const int*    eidx   = (const int*)d_in[11];

    const int N = in_sizes[2];
    const int E = in_sizes[10] / 2;
    const int* src_idx = eidx;
    const int* dst_idx = eidx + E;

    const int nbuck = (N + NPB - 1) >> NPB_LOG;

    // fast-path ws layout
    char* w = (char*)d_ws;
    float2* vp     = (float2*)w;                    w += (size_t)N * sizeof(float2);
    int*    counts = (int*)w;                       w += (size_t)nbuck * NBLK * sizeof(int);
    int*    scanned= (int*)w;                       w += (size_t)nbuck * NBLK * sizeof(int);
    int*    totals = (int*)w;                       w += (size_t)nbuck * sizeof(int);
    int*    basep  = (int*)w;                       w += (size_t)nbuck * sizeof(int);
    w = (char*)(((uintptr_t)w + 15) & ~(uintptr_t)15);
    uint2*  recs   = (uint2*)w;
    // expected records ~= E (Binomial(2E, 0.5)); cap with generous slack
    size_t rec_cap = (size_t)E + (size_t)E / 8;
    w += rec_cap * sizeof(uint2);
    size_t need_fast = (size_t)(w - (char*)d_ws);

    // fast path valid when: buckets fit, d fits in 20 bits, ws large enough
    if (nbuck <= MAXBUCK && N <= (1 << 20) && ws_size >= need_fast) {
        node_pre_fast<<<2048, 256, 0, stream>>>(v_x, p_x, vp, N);
        sweep_count<<<NBLK, SWT, 0, stream>>>(src_idx, ea, counts, nbuck, E);
        scan_rows<<<nbuck, NBLK, 0, stream>>>(counts, scanned, totals);
        scan_totals<<<1, 1024, 0, stream>>>(totals, basep, nbuck);
        sweep_scatter<<<NBLK, SWT, 0, stream>>>(ea, src_idx, dst_idx,
                                                scanned, basep, recs, nbuck, E);
        bucket_reduce<<<nbuck, 1024, 0, stream>>>(recs, basep, totals, vp,
                                                  p_x, p_prev, dt, (float*)d_out, N);
    } else {
        float2*  fvp  = (float2*)d_ws;
        double2* facc = (double2*)((char*)d_ws + (size_t)N * sizeof(float2));
        fb_node_pre<<<2048, 256, 0, stream>>>(v_x, p_x, fvp, facc, N);
        fb_edge_scatter<<<(E + 255) / 256, 256, 0, stream>>>(
            fvp, ea, src_idx, dst_idx, facc, E);
        fb_node_final<<<2048, 256, 0, stream>>>(
            facc, p_x, p_prev, dt, (float*)d_out, N);
    }
}

// Round 10
// 162.521 us; speedup vs baseline: 1.4385x; 1.4385x over previous
//
#include <hip/hip_runtime.h>

// CompressibleFluidLoss: out[i] = mean_x + mean_y + (p[i]-p_prev[i])/dt,
// vp = v*p per node; means are masked scatter-means over edges at src.
//
// Round 10: chunk-major record layout. Each 1024-thread block sorts its
// 4096-edge chunk by bucket entirely in LDS and flushes LINEARLY to a fixed
// per-chunk region (coalesced full-line writes; r8/r9's 2.7x scattered-write
// amplification gone). Per-(chunk,bucket) off/cnt matrices replace the whole
// count+scan pipeline (3 kernels deleted). bucket_reduce reads per-bucket
// runs (avg 16 recs = 128B contiguous), accumulates via ONE packed-f64 LDS
// atomic per record (sum + cnt*2^30), fused epilogue. Chunk overflow
// (> 4608 recs, >= +11 sigma) routes per-record to a packed-f64 global
// side accumulator — exact, never triggered in practice.

#define NPB      2048   // nodes per bucket
#define NPB_LOG  11
#define NBUCK_MAX 512
#define CE       4096   // edges per chunk
#define CB       1024   // chunk_sort block threads
#define EPT      4      // edges per thread
#define CCAP     4608   // record capacity per chunk region (mean 4096, +11s)
#define MAXCHUNK 2048
#define K_OFF    1073741824.0   // 2^30

// ---------------- fast path ----------------

__global__ void node_pre_fast(const float2* __restrict__ v,
                              const float* __restrict__ p,
                              float2* __restrict__ vp,
                              double2* __restrict__ side, int N) {
    int i = blockIdx.x * blockDim.x + threadIdx.x;
    int stride = gridDim.x * blockDim.x;
    for (; i < N; i += stride) {
        float2 vi = v[i];
        float pi = p[i];
        vp[i] = make_float2(vi.x * pi, vi.y * pi);
        side[i] = make_double2(0.0, 0.0);
    }
}

__device__ __forceinline__ void route_rec(uint2 r, int k, size_t rb, int slot,
                                          uint2* __restrict__ recs,
                                          const float2* __restrict__ vp,
                                          double2* __restrict__ side) {
    if (slot < CCAP) { recs[rb + slot] = r; return; }
    // overflow: accumulate exactly into global packed-f64 side accumulator
    unsigned sl = r.x & (NPB - 1u);
    bool diry = (r.x >> 11) & 1u;
    int d = (int)(r.x >> 12);
    float a = __uint_as_float(r.y);
    int s = k * NPB + (int)sl;
    float2 vpd = vp[d], vs = vp[s];
    float c = (diry ? vpd.y - vs.y : vpd.x - vs.x) / a;
    unsafeAtomicAdd(diry ? &side[s].y : &side[s].x, (double)c + K_OFF);
}

__global__ __launch_bounds__(CB) void chunk_sort(
        const float2* __restrict__ ea,
        const int* __restrict__ src_idx,
        const int* __restrict__ dst_idx,
        const float2* __restrict__ vp,
        uint2* __restrict__ recs,
        int* __restrict__ off_mat,
        int* __restrict__ cnt_mat,
        double2* __restrict__ side,
        int nbuck, int E) {
    __shared__ uint2 stage[CCAP];        // 36 KB
    __shared__ int hist[NBUCK_MAX];      // 2 KB
    __shared__ int tl[NBUCK_MAX];        // 2 KB
    __shared__ int cur[NBUCK_MAX];       // 2 KB
    int c = blockIdx.x, t = threadIdx.x;
    int e0 = c * CE;

    uint2 R0[EPT], R1[EPT];
    int K[EPT], NR[EPT];
#pragma unroll
    for (int i = 0; i < EPT; ++i) {
        int e = e0 + i * CB + t;         // coalesced per sub-iteration
        NR[i] = 0; K[i] = 0;
        if (e < E) {
            float2 a = ea[e];
            bool mx = (a.x != 0.f);
            bool my = (a.y != 0.f);
            if (mx || my) {
                int s = src_idx[e];
                int d = dst_idx[e];
                K[i] = s >> NPB_LOG;
                unsigned sl = (unsigned)(s & (NPB - 1));
                unsigned dm = (unsigned)d << 12;
                NR[i] = (int)mx + (int)my;
                uint2 rx = make_uint2(sl | dm, __float_as_uint(a.x));
                uint2 ry = make_uint2(sl | 0x800u | dm, __float_as_uint(a.y));
                R0[i] = mx ? rx : ry;
                R1[i] = ry;
            }
        }
    }
    if (t < nbuck) hist[t] = 0;
    __syncthreads();
#pragma unroll
    for (int i = 0; i < EPT; ++i)
        if (NR[i]) atomicAdd(&hist[K[i]], NR[i]);
    __syncthreads();
    // inclusive scan hist -> tl over nbuck (<= 512)
    if (t < nbuck) tl[t] = hist[t];
    __syncthreads();
    for (int off = 1; off < NBUCK_MAX; off <<= 1) {
        int x = 0;
        if (t < nbuck && t >= off) x = tl[t - off];
        __syncthreads();
        if (t < nbuck) tl[t] += x;
        __syncthreads();
    }
    int total = tl[nbuck - 1];
    if (t < nbuck) {
        int excl = tl[t] - hist[t];
        cur[t] = excl;
        off_mat[(size_t)c * nbuck + t] = excl;   // coalesced
        cnt_mat[(size_t)c * nbuck + t] = hist[t];
    }
    __syncthreads();
    size_t rb = (size_t)c * CCAP;
    if (total <= CCAP) {
        // stage grouped by bucket, then flush linearly (coalesced)
#pragma unroll
        for (int i = 0; i < EPT; ++i)
            if (NR[i]) {
                int slot = atomicAdd(&cur[K[i]], NR[i]);
                stage[slot] = R0[i];
                if (NR[i] == 2) stage[slot + 1] = R1[i];
            }
        __syncthreads();
        for (int j = t; j < total; j += CB) recs[rb + j] = stage[j];
    } else {
        // overflow regime (never in practice): direct writes + side routing
#pragma unroll
        for (int i = 0; i < EPT; ++i)
            if (NR[i]) {
                int slot = atomicAdd(&cur[K[i]], NR[i]);
                route_rec(R0[i], K[i], rb, slot, recs, vp, side);
                if (NR[i] == 2) route_rec(R1[i], K[i], rb, slot + 1, recs, vp, side);
            }
    }
}

__global__ __launch_bounds__(1024) void bucket_reduce(
        const uint2* __restrict__ recs,
        const int* __restrict__ off_mat,
        const int* __restrict__ cnt_mat,
        const float2* __restrict__ vp,
        const double2* __restrict__ side,
        const float* __restrict__ p,
        const float* __restrict__ p_prev,
        const float* __restrict__ dt_ptr,
        float* __restrict__ out,
        int nchunk, int nbuck, int N) {
    __shared__ float2 vps[NPB];      // 16 KB
    __shared__ double2 acc[NPB];     // 32 KB packed (sum + cnt*2^30)
    __shared__ int glen[MAXCHUNK];   // 8 KB -> inclusive prefix after scan
    __shared__ int goff[MAXCHUNK];   // 8 KB
    int k = blockIdx.x, t = threadIdx.x;
    int g0 = k * NPB;
    for (int i = t; i < NPB; i += 1024) {
        int g = g0 + i;
        vps[i] = (g < N) ? vp[g] : make_float2(0.f, 0.f);
        acc[i] = make_double2(0.0, 0.0);
    }
    for (int c = t; c < MAXCHUNK; c += 1024) {
        int len = 0, off = 0;
        if (c < nchunk) {
            off = off_mat[(size_t)c * nbuck + k];
            int cnt = cnt_mat[(size_t)c * nbuck + k];
            len = min(cnt, max(0, CCAP - off));   // clamp overflow'd tail
        }
        goff[c] = off;
        glen[c] = len;
    }
    __syncthreads();
    // inclusive scan glen over MAXCHUNK (2048) with 1024 threads
    for (int off = 1; off < MAXCHUNK; off <<= 1) {
        int i0 = t, i1 = t + 1024;
        int x0 = (i0 >= off) ? glen[i0 - off] : 0;
        int x1 = (i1 >= off) ? glen[i1 - off] : 0;
        __syncthreads();
        glen[i0] += x0;
        glen[i1] += x1;
        __syncthreads();
    }
    int total = glen[MAXCHUNK - 1];
    for (int idx = t; idx < total; idx += 1024) {
        // first chunk with inclusive prefix > idx
        int lo = 0, hi = nchunk - 1;
        while (lo < hi) {
            int mid = (lo + hi) >> 1;
            if (glen[mid] > idx) hi = mid; else lo = mid + 1;
        }
        int pre = lo ? glen[lo - 1] : 0;
        uint2 r = recs[(size_t)lo * CCAP + goff[lo] + (idx - pre)];
        unsigned sl = r.x & (NPB - 1u);
        bool diry = (r.x >> 11) & 1u;
        int d = (int)(r.x >> 12);
        float a = __uint_as_float(r.y);
        float2 vpd = vp[d];              // random 8B gather, L2/L3-resident
        float2 vs = vps[sl];
        float c = (diry ? vpd.y - vs.y : vpd.x - vs.x) / a;
        unsafeAtomicAdd(diry ? &acc[sl].y : &acc[sl].x, (double)c + K_OFF);
    }
    __syncthreads();
    float inv_dt = 1.0f / dt_ptr[0];
    for (int i = t; i < NPB; i += 1024) {
        int g = g0 + i;
        if (g < N) {
            double2 A = acc[i];
            double2 S = side[g];
            double Ax = A.x + S.x, Ay = A.y + S.y;
            double cx = rint(Ax * (1.0 / K_OFF));
            double sx = Ax - cx * K_OFF;
            double cy = rint(Ay * (1.0 / K_OFF));
            double sy = Ay - cy * K_OFF;
            out[g] = (float)(sx / fmax(cx, 1.0)) + (float)(sy / fmax(cy, 1.0))
                   + (p[g] - p_prev[g]) * inv_dt;
        }
    }
}

// ---------------- fallback path (round-5: f64-packed atomics, 390us) -------

__global__ void fb_node_pre(const float2* __restrict__ v,
                            const float* __restrict__ p,
                            float2* __restrict__ vp,
                            double2* __restrict__ acc, int N) {
    int i = blockIdx.x * blockDim.x + threadIdx.x;
    int stride = gridDim.x * blockDim.x;
    for (; i < N; i += stride) {
        float2 vi = v[i];
        float pi = p[i];
        vp[i] = make_float2(vi.x * pi, vi.y * pi);
        acc[i] = make_double2(0.0, 0.0);
    }
}

__global__ void fb_edge_scatter(const float2* __restrict__ vp,
                                const float2* __restrict__ ea,
                                const int* __restrict__ src_idx,
                                const int* __restrict__ dst_idx,
                                double2* __restrict__ acc, int E) {
    int e = blockIdx.x * blockDim.x + threadIdx.x;
    if (e >= E) return;
    float2 a = ea[e];
    bool mx = (a.x != 0.f);
    bool my = (a.y != 0.f);
    if (!mx && !my) return;
    int s = src_idx[e];
    int d = dst_idx[e];
    float2 vs = vp[s];
    float2 vd = vp[d];
    double* basep = (double*)&acc[s];
    if (mx) unsafeAtomicAdd(basep + 0, (double)((vd.x - vs.x) / a.x) + K_OFF);
    if (my) unsafeAtomicAdd(basep + 1, (double)((vd.y - vs.y) / a.y) + K_OFF);
}

__global__ void fb_node_final(const double2* __restrict__ acc,
                              const float* __restrict__ p,
                              const float* __restrict__ p_prev,
                              const float* __restrict__ dt_ptr,
                              float* __restrict__ out, int N) {
    int i = blockIdx.x * blockDim.x + threadIdx.x;
    int stride = gridDim.x * blockDim.x;
    float inv_dt = 1.0f / dt_ptr[0];
    for (; i < N; i += stride) {
        double2 A = acc[i];
        double cx = rint(A.x * (1.0 / K_OFF));
        double sx = A.x - cx * K_OFF;
        double cy = rint(A.y * (1.0 / K_OFF));
        double sy = A.y - cy * K_OFF;
        out[i] = (float)(sx / fmax(cx, 1.0)) + (float)(sy / fmax(cy, 1.0))
               + (p[i] - p_prev[i]) * inv_dt;
    }
}

// ---------------- launch ----------------

extern "C" void kernel_launch(void* const* d_in, const int* in_sizes, int n_in,
                              void* d_out, int out_size, void* d_ws, size_t ws_size,
                              hipStream_t stream) {
    const float2* v_x    = (const float2*)d_in[0];
    const float*  p_x    = (const float*)d_in[2];
    const float*  p_prev = (const float*)d_in[3];
    const float*  dt     = (const float*)d_in[9];
    const float2* ea     = (const float2*)d_in[10];
    const int*    eidx   = (const int*)d_in[11];

    const int N = in_sizes[2];
    const int E = in_sizes[10] / 2;
    const int* src_idx = eidx;
    const int* dst_idx = eidx + E;

    const int nbuck  = (N + NPB - 1) >> NPB_LOG;
    const int nchunk = (E + CE - 1) / CE;

    // ws layout (fast): vp 8MB | side 16MB | off 4MB | cnt 4MB | recs 75.5MB
    char* w = (char*)d_ws;
    float2*  vp      = (float2*)w;    w += (size_t)N * sizeof(float2);
    double2* side    = (double2*)w;   w += (size_t)N * sizeof(double2);
    int*     off_mat = (int*)w;       w += (size_t)nchunk * nbuck * sizeof(int);
    int*     cnt_mat = (int*)w;       w += (size_t)nchunk * nbuck * sizeof(int);
    w = (char*)(((uintptr_t)w + 15) & ~(uintptr_t)15);
    uint2*   recs    = (uint2*)w;     w += (size_t)nchunk * CCAP * sizeof(uint2);
    size_t need_fast = (size_t)(w - (char*)d_ws);

    if (nbuck <= NBUCK_MAX && nchunk <= MAXCHUNK && N <= (1 << 20)
        && ws_size >= need_fast) {
        node_pre_fast<<<2048, 256, 0, stream>>>(v_x, p_x, vp, side, N);
        chunk_sort<<<nchunk, CB, 0, stream>>>(ea, src_idx, dst_idx, vp, recs,
                                              off_mat, cnt_mat, side, nbuck, E);
        bucket_reduce<<<nbuck, 1024, 0, stream>>>(recs, off_mat, cnt_mat, vp,
                                                  side, p_x, p_prev, dt,
                                                  (float*)d_out, nchunk, nbuck, N);
    } else {
        float2*  fvp  = (float2*)d_ws;
        double2* facc = (double2*)((char*)d_ws + (size_t)N * sizeof(float2));
        fb_node_pre<<<2048, 256, 0, stream>>>(v_x, p_x, fvp, facc, N);
        fb_edge_scatter<<<(E + 255) / 256, 256, 0, stream>>>(
            fvp, ea, src_idx, dst_idx, facc, E);
        fb_node_final<<<2048, 256, 0, stream>>>(
            facc, p_x, p_prev, dt, (float*)d_out, N);
    }
}